// Round 1
// baseline (1144.113 us; speedup 1.0000x reference)
//
#include <hip/hip_runtime.h>

#define NN 50000
#define NE 800000
#define NG 2000
#define BN_EPS 1e-5f

__device__ __forceinline__ float lrelu(float v) { return v > 0.f ? v : 0.01f * v; }

// ---- aggr = (1+eps[l]) * x ; block 0 zeroes stats[256]
__global__ __launch_bounds__(256) void k_init(const float* __restrict__ x,
    const float* __restrict__ eps, int layer, float* __restrict__ aggr,
    float* __restrict__ stats)
{
    if (blockIdx.x == 0 && threadIdx.x < 256) stats[threadIdx.x] = 0.f;
    int tid = blockIdx.x * 256 + threadIdx.x;
    float s = 1.f + eps[layer];
    const float4* xv = (const float4*)x;
    float4* av = (float4*)aggr;
    for (int i = tid; i < NN * 16; i += gridDim.x * 256) {
        float4 v = xv[i];
        v.x *= s; v.y *= s; v.z *= s; v.w *= s;
        av[i] = v;
    }
}

// ---- per-edge: msg = relu(x[src] + edge_attr@We + be); atomicAdd into aggr[dst]
__global__ __launch_bounds__(256) void k_edge(
    const float* __restrict__ ea, const float* __restrict__ We,
    const float* __restrict__ be, const float* __restrict__ x,
    const int* __restrict__ src, const int* __restrict__ dst,
    float* __restrict__ aggr)
{
    __shared__ float ws[1024];
    __shared__ float bs[64];
    int t = threadIdx.x;
    for (int i = t; i < 1024; i += 256) ws[i] = We[i];
    if (t < 64) bs[t] = be[t];
    __syncthreads();
    int lane = t & 63;
    int wid = (blockIdx.x * 256 + t) >> 6;
    int nw  = (gridDim.x * 256) >> 6;
    for (int e = wid; e < NE; e += nw) {
        const float4* ap = (const float4*)(ea + (size_t)e * 16);
        float4 a0 = ap[0], a1 = ap[1], a2 = ap[2], a3 = ap[3];
        float acc = bs[lane];
        acc = fmaf(a0.x, ws[lane      ], acc);
        acc = fmaf(a0.y, ws[64  + lane], acc);
        acc = fmaf(a0.z, ws[128 + lane], acc);
        acc = fmaf(a0.w, ws[192 + lane], acc);
        acc = fmaf(a1.x, ws[256 + lane], acc);
        acc = fmaf(a1.y, ws[320 + lane], acc);
        acc = fmaf(a1.z, ws[384 + lane], acc);
        acc = fmaf(a1.w, ws[448 + lane], acc);
        acc = fmaf(a2.x, ws[512 + lane], acc);
        acc = fmaf(a2.y, ws[576 + lane], acc);
        acc = fmaf(a2.z, ws[640 + lane], acc);
        acc = fmaf(a2.w, ws[704 + lane], acc);
        acc = fmaf(a3.x, ws[768 + lane], acc);
        acc = fmaf(a3.y, ws[832 + lane], acc);
        acc = fmaf(a3.z, ws[896 + lane], acc);
        acc = fmaf(a3.w, ws[960 + lane], acc);
        int sn = src[e], dn = dst[e];
        float m = x[(size_t)sn * 64 + lane] + acc;
        m = m > 0.f ? m : 0.f;
        atomicAdd(&aggr[(size_t)dn * 64 + lane], m);
    }
}

// ---- [N,64]@[64,64]+b. PRE=1: apply BN(statsIn,g,b)+lrelu to input rows.
// POST=0: write raw + accumulate per-channel sum/sumsq into statsOut.
// POST=1: write lrelu(h), no stats.
template<int PRE, int POST>
__global__ __launch_bounds__(128) void k_mm64(
    const float* __restrict__ in, const float* __restrict__ W,
    const float* __restrict__ bias, const float* __restrict__ statsIn,
    const float* __restrict__ gIn, const float* __restrict__ bIn,
    float* __restrict__ out, float* __restrict__ statsOut)
{
    __shared__ float tile[128 * 65];
    __shared__ float sc[64], sh[64];
    int t = threadIdx.x;
    int base = blockIdx.x * 128;
    if (PRE) {
        if (t < 64) {
            float m = statsIn[t] * (1.f / NN);
            float v = statsIn[64 + t] * (1.f / NN) - m * m;
            float s = gIn[t] * rsqrtf(v + BN_EPS);
            sc[t] = s; sh[t] = bIn[t] - m * s;
        }
        __syncthreads();
    }
    for (int i = t; i < 2048; i += 128) {
        int row = i >> 4, c4 = (i & 15) << 2;
        int node = base + row;
        float4 v = {0.f, 0.f, 0.f, 0.f};
        if (node < NN) v = *(const float4*)(in + (size_t)node * 64 + c4);
        if (PRE) {
            v.x = lrelu(fmaf(v.x, sc[c4 + 0], sh[c4 + 0]));
            v.y = lrelu(fmaf(v.y, sc[c4 + 1], sh[c4 + 1]));
            v.z = lrelu(fmaf(v.z, sc[c4 + 2], sh[c4 + 2]));
            v.w = lrelu(fmaf(v.w, sc[c4 + 3], sh[c4 + 3]));
        }
        float* p = &tile[row * 65 + c4];
        p[0] = v.x; p[1] = v.y; p[2] = v.z; p[3] = v.w;
    }
    __syncthreads();
    float acc[64];
    #pragma unroll
    for (int c = 0; c < 64; ++c) acc[c] = bias[c];
    {
        const float* r = &tile[t * 65];
        for (int k = 0; k < 64; ++k) {
            float hk = r[k];
            #pragma unroll
            for (int c = 0; c < 64; ++c) acc[c] = fmaf(hk, W[k * 64 + c], acc[c]);
        }
    }
    __syncthreads();
    int node = base + t;
    bool valid = node < NN;
    #pragma unroll
    for (int c = 0; c < 64; ++c) tile[t * 65 + c] = valid ? acc[c] : 0.f;
    __syncthreads();
    for (int i = t; i < 2048; i += 128) {
        int row = i >> 4, c4 = (i & 15) << 2;
        int n2 = base + row;
        if (n2 < NN) {
            const float* p = &tile[row * 65 + c4];
            float4 v = {p[0], p[1], p[2], p[3]};
            if (POST == 1) { v.x = lrelu(v.x); v.y = lrelu(v.y); v.z = lrelu(v.z); v.w = lrelu(v.w); }
            *(float4*)(out + (size_t)n2 * 64 + c4) = v;
        }
    }
    if (POST == 0) {
        int c = t & 63, g = t >> 6;
        float s = 0.f, q = 0.f;
        for (int rr = 0; rr < 64; ++rr) {
            float v = tile[(g * 64 + rr) * 65 + c];
            s += v; q += v * v;
        }
        atomicAdd(&statsOut[c], s);
        atomicAdd(&statsOut[64 + c], q);
    }
}

// ---- elementwise x = lrelu(bn(h)) using stats
__global__ __launch_bounds__(256) void k_bn(
    const float* __restrict__ in, const float* __restrict__ stats,
    const float* __restrict__ g, const float* __restrict__ b,
    float* __restrict__ out)
{
    int tid = blockIdx.x * 256 + threadIdx.x;
    for (int i = tid; i < NN * 16; i += gridDim.x * 256) {
        int c4 = (i & 15) << 2;
        float4 v = ((const float4*)in)[i];
        float o[4] = {v.x, v.y, v.z, v.w};
        #pragma unroll
        for (int j = 0; j < 4; ++j) {
            int c = c4 + j;
            float m = stats[c] * (1.f / NN);
            float vv = stats[64 + c] * (1.f / NN) - m * m;
            float s = g[c] * rsqrtf(vv + BN_EPS);
            o[j] = lrelu(fmaf(o[j] - m, s, b[c]));
        }
        float4 r = {o[0], o[1], o[2], o[3]};
        ((float4*)out)[i] = r;
    }
}

__global__ __launch_bounds__(256) void k_zero(float* __restrict__ p, int n)
{
    int tid = blockIdx.x * 256 + threadIdx.x;
    for (int i = tid; i < n; i += gridDim.x * 256) p[i] = 0.f;
}

__global__ __launch_bounds__(256) void k_pool(
    const float* __restrict__ x, const int* __restrict__ batch,
    float* __restrict__ pool)
{
    int lane = threadIdx.x & 63;
    int wid = (blockIdx.x * 256 + threadIdx.x) >> 6;
    int nw = (gridDim.x * 256) >> 6;
    for (int n = wid; n < NN; n += nw) {
        int gi = batch[n];
        atomicAdd(&pool[(size_t)gi * 64 + lane], x[(size_t)n * 64 + lane]);
    }
}

// ---- [N,128]@[128,128]+b with stats. MODE0: input = concat(x, pool[batch]).
// MODE1: input = lrelu(bn(h128; statsIn,g,b)).
template<int MODE>
__global__ __launch_bounds__(128) void k_cmm(
    const float* __restrict__ inA, const float* __restrict__ pool,
    const int* __restrict__ batch, const float* __restrict__ statsIn,
    const float* __restrict__ gIn, const float* __restrict__ bIn,
    const float* __restrict__ W, const float* __restrict__ bias,
    float* __restrict__ out, float* __restrict__ statsOut)
{
    __shared__ float tile[64 * 129];
    __shared__ float sc[128], sh[128];
    int t = threadIdx.x;
    int base = blockIdx.x * 64;
    if (MODE == 1) {
        float m = statsIn[t] * (1.f / NN);
        float v = statsIn[128 + t] * (1.f / NN) - m * m;
        float s = gIn[t] * rsqrtf(v + BN_EPS);
        sc[t] = s; sh[t] = bIn[t] - m * s;
        __syncthreads();
    }
    for (int i = t; i < 64 * 32; i += 128) {
        int row = i >> 5, c4 = (i & 31) << 2;
        int node = base + row;
        float4 v = {0.f, 0.f, 0.f, 0.f};
        if (node < NN) {
            if (MODE == 0) {
                if (c4 < 64) v = *(const float4*)(inA + (size_t)node * 64 + c4);
                else         v = *(const float4*)(pool + (size_t)batch[node] * 64 + (c4 - 64));
            } else {
                v = *(const float4*)(inA + (size_t)node * 128 + c4);
                v.x = lrelu(fmaf(v.x, sc[c4 + 0], sh[c4 + 0]));
                v.y = lrelu(fmaf(v.y, sc[c4 + 1], sh[c4 + 1]));
                v.z = lrelu(fmaf(v.z, sc[c4 + 2], sh[c4 + 2]));
                v.w = lrelu(fmaf(v.w, sc[c4 + 3], sh[c4 + 3]));
            }
        }
        float* p = &tile[row * 129 + c4];
        p[0] = v.x; p[1] = v.y; p[2] = v.z; p[3] = v.w;
    }
    __syncthreads();
    int lane = t & 63, half = t >> 6;
    float acc[64];
    #pragma unroll
    for (int c = 0; c < 64; ++c) acc[c] = bias[half * 64 + c];
    {
        const float* r = &tile[lane * 129];
        for (int k = 0; k < 128; ++k) {
            float hk = r[k];
            #pragma unroll
            for (int c = 0; c < 64; ++c) acc[c] = fmaf(hk, W[k * 128 + half * 64 + c], acc[c]);
        }
    }
    __syncthreads();
    int node = base + lane;
    bool valid = node < NN;
    #pragma unroll
    for (int c = 0; c < 64; ++c) tile[lane * 129 + half * 64 + c] = valid ? acc[c] : 0.f;
    __syncthreads();
    for (int i = t; i < 64 * 32; i += 128) {
        int row = i >> 5, c4 = (i & 31) << 2;
        int n2 = base + row;
        if (n2 < NN) {
            const float* p = &tile[row * 129 + c4];
            float4 v = {p[0], p[1], p[2], p[3]};
            *(float4*)(out + (size_t)n2 * 128 + c4) = v;
        }
    }
    {
        float s = 0.f, q = 0.f;
        for (int rr = 0; rr < 64; ++rr) {
            float v = tile[rr * 129 + t];
            s += v; q += v * v;
        }
        atomicAdd(&statsOut[t], s);
        atomicAdd(&statsOut[128 + t], q);
    }
}

// ---- out[n] = lrelu(bn(h128[n])) . cW3 + cb3
__global__ __launch_bounds__(256) void k_out(
    const float* __restrict__ h, const float* __restrict__ stats,
    const float* __restrict__ g, const float* __restrict__ b,
    const float* __restrict__ W3, const float* __restrict__ b3,
    float* __restrict__ outv)
{
    int lane = threadIdx.x & 63;
    int wid = (blockIdx.x * 256 + threadIdx.x) >> 6;
    int nw = (gridDim.x * 256) >> 6;
    float m0 = stats[lane] * (1.f / NN);
    float v0 = stats[128 + lane] * (1.f / NN) - m0 * m0;
    float s0 = g[lane] * rsqrtf(v0 + BN_EPS);
    float h0 = b[lane] - m0 * s0;
    float m1 = stats[64 + lane] * (1.f / NN);
    float v1 = stats[128 + 64 + lane] * (1.f / NN) - m1 * m1;
    float s1 = g[64 + lane] * rsqrtf(v1 + BN_EPS);
    float h1 = b[64 + lane] - m1 * s1;
    float w0 = W3[lane], w1 = W3[64 + lane];
    float bb = b3[0];
    for (int n = wid; n < NN; n += nw) {
        float a = h[(size_t)n * 128 + lane];
        float c = h[(size_t)n * 128 + 64 + lane];
        a = lrelu(fmaf(a, s0, h0));
        c = lrelu(fmaf(c, s1, h1));
        float p = a * w0 + c * w1;
        p += __shfl_xor(p, 32);
        p += __shfl_xor(p, 16);
        p += __shfl_xor(p, 8);
        p += __shfl_xor(p, 4);
        p += __shfl_xor(p, 2);
        p += __shfl_xor(p, 1);
        if (lane == 0) outv[n] = p + bb;
    }
}

extern "C" void kernel_launch(void* const* d_in, const int* in_sizes, int n_in,
                              void* d_out, int out_size, void* d_ws, size_t ws_size,
                              hipStream_t stream)
{
    const float* x0   = (const float*)d_in[0];
    const float* ea   = (const float*)d_in[1];
    const float* leW  = (const float*)d_in[2];
    const float* leb  = (const float*)d_in[3];
    const float* W1   = (const float*)d_in[4];
    const float* b1   = (const float*)d_in[5];
    const float* g1   = (const float*)d_in[6];
    const float* bb1  = (const float*)d_in[7];
    const float* W2   = (const float*)d_in[8];
    const float* b2   = (const float*)d_in[9];
    const float* eps  = (const float*)d_in[10];
    const float* og   = (const float*)d_in[11];
    const float* ob   = (const float*)d_in[12];
    const float* cW1  = (const float*)d_in[13];
    const float* cb1  = (const float*)d_in[14];
    const float* cg1  = (const float*)d_in[15];
    const float* cbb1 = (const float*)d_in[16];
    const float* cW2  = (const float*)d_in[17];
    const float* cb2  = (const float*)d_in[18];
    const float* cg2  = (const float*)d_in[19];
    const float* cbb2 = (const float*)d_in[20];
    const float* cW3  = (const float*)d_in[21];
    const float* cb3  = (const float*)d_in[22];
    const int* ei     = (const int*)d_in[23];
    const int* batch  = (const int*)d_in[24];
    const int* src = ei;
    const int* dst = ei + NE;

    float* xbuf   = (float*)d_ws;                     // [NN*64]
    float* hbuf   = xbuf + (size_t)NN * 64;           // [NN*64]
    float* h128   = hbuf + (size_t)NN * 64;           // [NN*128]
    float* pool   = h128 + (size_t)NN * 128;          // [NG*64]
    float* cstats = pool + (size_t)NG * 64;           // [512]
    float* stats  = cstats + 512;                     // [256]
    float* outp   = (float*)d_out;

    int mmGrid = (NN + 127) / 128;  // 391
    int cGrid  = (NN + 63) / 64;    // 782

    for (int l = 0; l < 3; ++l) {
        const float* xc = (l == 0) ? x0 : xbuf;
        k_init<<<1024, 256, 0, stream>>>(xc, eps, l, hbuf, stats);
        k_edge<<<2048, 256, 0, stream>>>(ea, leW + l * 1024, leb + l * 64, xc, src, dst, hbuf);
        k_mm64<0, 0><<<mmGrid, 128, 0, stream>>>(hbuf, W1 + l * 4096, b1 + l * 64,
                nullptr, nullptr, nullptr, hbuf, stats);
        if (l < 2) {
            k_mm64<1, 0><<<mmGrid, 128, 0, stream>>>(hbuf, W2 + l * 4096, b2 + l * 64,
                    stats, g1 + l * 64, bb1 + l * 64, hbuf, stats + 128);
            k_bn<<<1024, 256, 0, stream>>>(hbuf, stats + 128, og + l * 64, ob + l * 64, xbuf);
        } else {
            k_mm64<1, 1><<<mmGrid, 128, 0, stream>>>(hbuf, W2 + l * 4096, b2 + l * 64,
                    stats, g1 + l * 64, bb1 + l * 64, xbuf, nullptr);
        }
    }
    k_zero<<<512, 256, 0, stream>>>(pool, NG * 64 + 512);
    k_pool<<<1024, 256, 0, stream>>>(xbuf, batch, pool);
    k_cmm<0><<<cGrid, 128, 0, stream>>>(xbuf, pool, batch, nullptr, nullptr, nullptr,
                                        cW1, cb1, h128, cstats);
    k_cmm<1><<<cGrid, 128, 0, stream>>>(h128, nullptr, nullptr, cstats, cg1, cbb1,
                                        cW2, cb2, h128, cstats + 256);
    k_out<<<1024, 256, 0, stream>>>(h128, cstats + 256, cg2, cbb2, cW3, cb3, outp);
}

// Round 2
// 1075.414 us; speedup vs baseline: 1.0639x; 1.0639x over previous
//
#include <hip/hip_runtime.h>

#define NN 50000
#define NE 800000
#define NG 2000
#define BN_EPS 1e-5f
#define NB_SCAN 196  // ceil(NN/256)

__device__ __forceinline__ float lrelu(float v) { return v > 0.f ? v : 0.01f * v; }

// ---- zero the regions that must start at 0 each call: pool+cstats+stats+cnt
__global__ __launch_bounds__(256) void k_prep(int* __restrict__ p, int n)
{
    int tid = blockIdx.x * 256 + threadIdx.x;
    for (int i = tid; i < n; i += gridDim.x * 256) p[i] = 0;
}

// ---- histogram of dst
__global__ __launch_bounds__(256) void k_hist(const int* __restrict__ dst, int* __restrict__ cnt)
{
    int tid = blockIdx.x * 256 + threadIdx.x;
    for (int e = tid; e < NE; e += gridDim.x * 256) atomicAdd(&cnt[dst[e]], 1);
}

// ---- per-block inclusive scan of cnt -> off[i+1] (local), block sums -> bsum
__global__ __launch_bounds__(256) void k_scanA(const int* __restrict__ cnt,
    int* __restrict__ off, int* __restrict__ bsum)
{
    __shared__ int s[256];
    int t = threadIdx.x;
    int i = blockIdx.x * 256 + t;
    int v = (i < NN) ? cnt[i] : 0;
    s[t] = v; __syncthreads();
    #pragma unroll
    for (int d = 1; d < 256; d <<= 1) {
        int u = (t >= d) ? s[t - d] : 0;
        __syncthreads();
        s[t] += u;
        __syncthreads();
    }
    if (i < NN) off[i + 1] = s[t];
    if (t == 255) bsum[blockIdx.x] = s[255];
}

// ---- single-block exclusive scan of bsum -> boff
__global__ __launch_bounds__(256) void k_scanB(const int* __restrict__ bsum, int* __restrict__ boff)
{
    __shared__ int s[256];
    int t = threadIdx.x;
    int v = (t < NB_SCAN) ? bsum[t] : 0;
    s[t] = v; __syncthreads();
    #pragma unroll
    for (int d = 1; d < 256; d <<= 1) {
        int u = (t >= d) ? s[t - d] : 0;
        __syncthreads();
        s[t] += u;
        __syncthreads();
    }
    boff[t] = s[t] - v;
}

// ---- globalize: off[i+1] += boff[block]; cur[i] = segment start; off[0]=0
__global__ __launch_bounds__(256) void k_scanC(const int* __restrict__ cnt,
    int* __restrict__ off, const int* __restrict__ boff, int* __restrict__ cur)
{
    int i = blockIdx.x * 256 + threadIdx.x;
    if (i < NN) {
        int incl = off[i + 1] + boff[blockIdx.x];
        off[i + 1] = incl;
        cur[i] = incl - cnt[i];
    }
    if (i == 0) off[0] = 0;
}

// ---- scatter edge ids into dst-sorted order
__global__ __launch_bounds__(256) void k_scatter(const int* __restrict__ src,
    const int* __restrict__ dst, int* __restrict__ cur,
    int* __restrict__ perm, int* __restrict__ srcs)
{
    int tid = blockIdx.x * 256 + threadIdx.x;
    for (int e = tid; e < NE; e += gridDim.x * 256) {
        int d = dst[e];
        int p = atomicAdd(&cur[d], 1);
        perm[p] = e;
        srcs[p] = src[e];
    }
}

// ---- wave-per-node aggregation: aggr[n] = (1+eps)*x[n] + sum_e relu(x[src]+ea@We+be)
__global__ __launch_bounds__(256) void k_aggr(
    const float* __restrict__ x, const float* __restrict__ ea,
    const float* __restrict__ We, const float* __restrict__ be,
    const int* __restrict__ off, const int* __restrict__ srcs,
    const int* __restrict__ perm, const float* __restrict__ eps, int layer,
    float* __restrict__ aggr)
{
    __shared__ float ws[1024];   // transposed: ws[c*16+k] = We[k*64+c]
    __shared__ float bs[64];
    int t = threadIdx.x;
    for (int i = t; i < 1024; i += 256) {
        int c = i >> 4, k = i & 15;
        ws[i] = We[k * 64 + c];
    }
    if (t < 64) bs[t] = be[t];
    __syncthreads();
    int lane = t & 63;
    int n = blockIdx.x * 4 + (t >> 6);
    if (n >= NN) return;
    float acc = (1.f + eps[layer]) * x[(size_t)n * 64 + lane];
    int p0 = off[n], p1 = off[n + 1];
    float bias = bs[lane];
    const float4* wv = (const float4*)(ws + lane * 16);
    float4 w0 = wv[0], w1 = wv[1], w2 = wv[2], w3 = wv[3];
    for (int p = p0; p < p1; ++p) {
        int e = perm[p];
        int s = srcs[p];
        const float4* ap = (const float4*)(ea + (size_t)e * 16);
        float4 a0 = ap[0], a1 = ap[1], a2 = ap[2], a3 = ap[3];
        float xs = x[(size_t)s * 64 + lane];
        float m = bias;
        m = fmaf(a0.x, w0.x, m); m = fmaf(a0.y, w0.y, m);
        m = fmaf(a0.z, w0.z, m); m = fmaf(a0.w, w0.w, m);
        m = fmaf(a1.x, w1.x, m); m = fmaf(a1.y, w1.y, m);
        m = fmaf(a1.z, w1.z, m); m = fmaf(a1.w, w1.w, m);
        m = fmaf(a2.x, w2.x, m); m = fmaf(a2.y, w2.y, m);
        m = fmaf(a2.z, w2.z, m); m = fmaf(a2.w, w2.w, m);
        m = fmaf(a3.x, w3.x, m); m = fmaf(a3.y, w3.y, m);
        m = fmaf(a3.z, w3.z, m); m = fmaf(a3.w, w3.w, m);
        m += xs;
        acc += fmaxf(m, 0.f);
    }
    aggr[(size_t)n * 64 + lane] = acc;
}

// ---- [N,64]@[64,64]+b. PRE=1: apply BN(statsIn,g,b)+lrelu to input rows.
// POST=0: write raw + accumulate per-channel sum/sumsq into statsOut.
// POST=1: write lrelu(h), no stats.
template<int PRE, int POST>
__global__ __launch_bounds__(128) void k_mm64(
    const float* __restrict__ in, const float* __restrict__ W,
    const float* __restrict__ bias, const float* __restrict__ statsIn,
    const float* __restrict__ gIn, const float* __restrict__ bIn,
    float* __restrict__ out, float* __restrict__ statsOut)
{
    __shared__ float tile[128 * 65];
    __shared__ float sc[64], sh[64];
    int t = threadIdx.x;
    int base = blockIdx.x * 128;
    if (PRE) {
        if (t < 64) {
            float m = statsIn[t] * (1.f / NN);
            float v = statsIn[64 + t] * (1.f / NN) - m * m;
            float s = gIn[t] * rsqrtf(v + BN_EPS);
            sc[t] = s; sh[t] = bIn[t] - m * s;
        }
        __syncthreads();
    }
    for (int i = t; i < 2048; i += 128) {
        int row = i >> 4, c4 = (i & 15) << 2;
        int node = base + row;
        float4 v = {0.f, 0.f, 0.f, 0.f};
        if (node < NN) v = *(const float4*)(in + (size_t)node * 64 + c4);
        if (PRE) {
            v.x = lrelu(fmaf(v.x, sc[c4 + 0], sh[c4 + 0]));
            v.y = lrelu(fmaf(v.y, sc[c4 + 1], sh[c4 + 1]));
            v.z = lrelu(fmaf(v.z, sc[c4 + 2], sh[c4 + 2]));
            v.w = lrelu(fmaf(v.w, sc[c4 + 3], sh[c4 + 3]));
        }
        float* p = &tile[row * 65 + c4];
        p[0] = v.x; p[1] = v.y; p[2] = v.z; p[3] = v.w;
    }
    __syncthreads();
    float acc[64];
    #pragma unroll
    for (int c = 0; c < 64; ++c) acc[c] = bias[c];
    {
        const float* r = &tile[t * 65];
        for (int k = 0; k < 64; ++k) {
            float hk = r[k];
            #pragma unroll
            for (int c = 0; c < 64; ++c) acc[c] = fmaf(hk, W[k * 64 + c], acc[c]);
        }
    }
    __syncthreads();
    int node = base + t;
    bool valid = node < NN;
    #pragma unroll
    for (int c = 0; c < 64; ++c) tile[t * 65 + c] = valid ? acc[c] : 0.f;
    __syncthreads();
    for (int i = t; i < 2048; i += 128) {
        int row = i >> 4, c4 = (i & 15) << 2;
        int n2 = base + row;
        if (n2 < NN) {
            const float* p = &tile[row * 65 + c4];
            float4 v = {p[0], p[1], p[2], p[3]};
            if (POST == 1) { v.x = lrelu(v.x); v.y = lrelu(v.y); v.z = lrelu(v.z); v.w = lrelu(v.w); }
            *(float4*)(out + (size_t)n2 * 64 + c4) = v;
        }
    }
    if (POST == 0) {
        int c = t & 63, g = t >> 6;
        float s = 0.f, q = 0.f;
        for (int rr = 0; rr < 64; ++rr) {
            float v = tile[(g * 64 + rr) * 65 + c];
            s += v; q += v * v;
        }
        atomicAdd(&statsOut[c], s);
        atomicAdd(&statsOut[64 + c], q);
    }
}

// ---- elementwise x = lrelu(bn(h)) using stats
__global__ __launch_bounds__(256) void k_bn(
    const float* __restrict__ in, const float* __restrict__ stats,
    const float* __restrict__ g, const float* __restrict__ b,
    float* __restrict__ out)
{
    int tid = blockIdx.x * 256 + threadIdx.x;
    for (int i = tid; i < NN * 16; i += gridDim.x * 256) {
        int c4 = (i & 15) << 2;
        float4 v = ((const float4*)in)[i];
        float o[4] = {v.x, v.y, v.z, v.w};
        #pragma unroll
        for (int j = 0; j < 4; ++j) {
            int c = c4 + j;
            float m = stats[c] * (1.f / NN);
            float vv = stats[64 + c] * (1.f / NN) - m * m;
            float s = g[c] * rsqrtf(vv + BN_EPS);
            o[j] = lrelu(fmaf(o[j] - m, s, b[c]));
        }
        float4 r = {o[0], o[1], o[2], o[3]};
        ((float4*)out)[i] = r;
    }
}

__global__ __launch_bounds__(256) void k_pool(
    const float* __restrict__ x, const int* __restrict__ batch,
    float* __restrict__ pool)
{
    int lane = threadIdx.x & 63;
    int wid = (blockIdx.x * 256 + threadIdx.x) >> 6;
    int nw = (gridDim.x * 256) >> 6;
    for (int n = wid; n < NN; n += nw) {
        int gi = batch[n];
        atomicAdd(&pool[(size_t)gi * 64 + lane], x[(size_t)n * 64 + lane]);
    }
}

// ---- [N,128]@[128,128]+b with stats. MODE0: input = concat(x, pool[batch]).
// MODE1: input = lrelu(bn(h128; statsIn,g,b)).
template<int MODE>
__global__ __launch_bounds__(128) void k_cmm(
    const float* __restrict__ inA, const float* __restrict__ pool,
    const int* __restrict__ batch, const float* __restrict__ statsIn,
    const float* __restrict__ gIn, const float* __restrict__ bIn,
    const float* __restrict__ W, const float* __restrict__ bias,
    float* __restrict__ out, float* __restrict__ statsOut)
{
    __shared__ float tile[64 * 129];
    __shared__ float sc[128], sh[128];
    int t = threadIdx.x;
    int base = blockIdx.x * 64;
    if (MODE == 1) {
        float m = statsIn[t] * (1.f / NN);
        float v = statsIn[128 + t] * (1.f / NN) - m * m;
        float s = gIn[t] * rsqrtf(v + BN_EPS);
        sc[t] = s; sh[t] = bIn[t] - m * s;
        __syncthreads();
    }
    for (int i = t; i < 64 * 32; i += 128) {
        int row = i >> 5, c4 = (i & 31) << 2;
        int node = base + row;
        float4 v = {0.f, 0.f, 0.f, 0.f};
        if (node < NN) {
            if (MODE == 0) {
                if (c4 < 64) v = *(const float4*)(inA + (size_t)node * 64 + c4);
                else         v = *(const float4*)(pool + (size_t)batch[node] * 64 + (c4 - 64));
            } else {
                v = *(const float4*)(inA + (size_t)node * 128 + c4);
                v.x = lrelu(fmaf(v.x, sc[c4 + 0], sh[c4 + 0]));
                v.y = lrelu(fmaf(v.y, sc[c4 + 1], sh[c4 + 1]));
                v.z = lrelu(fmaf(v.z, sc[c4 + 2], sh[c4 + 2]));
                v.w = lrelu(fmaf(v.w, sc[c4 + 3], sh[c4 + 3]));
            }
        }
        float* p = &tile[row * 129 + c4];
        p[0] = v.x; p[1] = v.y; p[2] = v.z; p[3] = v.w;
    }
    __syncthreads();
    int lane = t & 63, half = t >> 6;
    float acc[64];
    #pragma unroll
    for (int c = 0; c < 64; ++c) acc[c] = bias[half * 64 + c];
    {
        const float* r = &tile[lane * 129];
        for (int k = 0; k < 128; ++k) {
            float hk = r[k];
            #pragma unroll
            for (int c = 0; c < 64; ++c) acc[c] = fmaf(hk, W[k * 128 + half * 64 + c], acc[c]);
        }
    }
    __syncthreads();
    int node = base + lane;
    bool valid = node < NN;
    #pragma unroll
    for (int c = 0; c < 64; ++c) tile[lane * 129 + half * 64 + c] = valid ? acc[c] : 0.f;
    __syncthreads();
    for (int i = t; i < 64 * 32; i += 128) {
        int row = i >> 5, c4 = (i & 31) << 2;
        int n2 = base + row;
        if (n2 < NN) {
            const float* p = &tile[row * 129 + c4];
            float4 v = {p[0], p[1], p[2], p[3]};
            *(float4*)(out + (size_t)n2 * 128 + c4) = v;
        }
    }
    {
        float s = 0.f, q = 0.f;
        for (int rr = 0; rr < 64; ++rr) {
            float v = tile[rr * 129 + t];
            s += v; q += v * v;
        }
        atomicAdd(&statsOut[t], s);
        atomicAdd(&statsOut[128 + t], q);
    }
}

// ---- out[n] = lrelu(bn(h128[n])) . cW3 + cb3
__global__ __launch_bounds__(256) void k_out(
    const float* __restrict__ h, const float* __restrict__ stats,
    const float* __restrict__ g, const float* __restrict__ b,
    const float* __restrict__ W3, const float* __restrict__ b3,
    float* __restrict__ outv)
{
    int lane = threadIdx.x & 63;
    int wid = (blockIdx.x * 256 + threadIdx.x) >> 6;
    int nw = (gridDim.x * 256) >> 6;
    float m0 = stats[lane] * (1.f / NN);
    float v0 = stats[128 + lane] * (1.f / NN) - m0 * m0;
    float s0 = g[lane] * rsqrtf(v0 + BN_EPS);
    float h0 = b[lane] - m0 * s0;
    float m1 = stats[64 + lane] * (1.f / NN);
    float v1 = stats[128 + 64 + lane] * (1.f / NN) - m1 * m1;
    float s1 = g[64 + lane] * rsqrtf(v1 + BN_EPS);
    float h1 = b[64 + lane] - m1 * s1;
    float w0 = W3[lane], w1 = W3[64 + lane];
    float bb = b3[0];
    for (int n = wid; n < NN; n += nw) {
        float a = h[(size_t)n * 128 + lane];
        float c = h[(size_t)n * 128 + 64 + lane];
        a = lrelu(fmaf(a, s0, h0));
        c = lrelu(fmaf(c, s1, h1));
        float p = a * w0 + c * w1;
        p += __shfl_xor(p, 32);
        p += __shfl_xor(p, 16);
        p += __shfl_xor(p, 8);
        p += __shfl_xor(p, 4);
        p += __shfl_xor(p, 2);
        p += __shfl_xor(p, 1);
        if (lane == 0) outv[n] = p + bb;
    }
}

extern "C" void kernel_launch(void* const* d_in, const int* in_sizes, int n_in,
                              void* d_out, int out_size, void* d_ws, size_t ws_size,
                              hipStream_t stream)
{
    const float* x0   = (const float*)d_in[0];
    const float* ea   = (const float*)d_in[1];
    const float* leW  = (const float*)d_in[2];
    const float* leb  = (const float*)d_in[3];
    const float* W1   = (const float*)d_in[4];
    const float* b1   = (const float*)d_in[5];
    const float* g1   = (const float*)d_in[6];
    const float* bb1  = (const float*)d_in[7];
    const float* W2   = (const float*)d_in[8];
    const float* b2   = (const float*)d_in[9];
    const float* eps  = (const float*)d_in[10];
    const float* og   = (const float*)d_in[11];
    const float* ob   = (const float*)d_in[12];
    const float* cW1  = (const float*)d_in[13];
    const float* cb1  = (const float*)d_in[14];
    const float* cg1  = (const float*)d_in[15];
    const float* cbb1 = (const float*)d_in[16];
    const float* cW2  = (const float*)d_in[17];
    const float* cb2  = (const float*)d_in[18];
    const float* cg2  = (const float*)d_in[19];
    const float* cbb2 = (const float*)d_in[20];
    const float* cW3  = (const float*)d_in[21];
    const float* cb3  = (const float*)d_in[22];
    const int* ei     = (const int*)d_in[23];
    const int* batch  = (const int*)d_in[24];
    const int* src = ei;
    const int* dst = ei + NE;

    // ---- workspace layout (4-byte units)
    float* xbuf   = (float*)d_ws;                      // 3,200,000
    float* hbuf   = xbuf + (size_t)NN * 64;            // 3,200,000
    float* h128   = hbuf + (size_t)NN * 64;            // 6,400,000
    float* pool   = h128 + (size_t)NN * 128;           // 128,000
    float* cstats = pool + (size_t)NG * 64;            // 512
    float* stats  = cstats + 512;                      // 768 (3 layers x 256)
    int*   cnt    = (int*)(stats + 768);               // NN
    int*   off    = cnt + NN;                          // NN+1 (+pad)
    int*   cur    = off + NN + 4;                      // NN
    int*   bsum   = cur + NN;                          // 256
    int*   boff   = bsum + 256;                        // 256
    int*   srcs   = boff + 256;                        // NE
    int*   perm   = srcs + NE;                         // NE
    float* outp   = (float*)d_out;

    int zeroN = NG * 64 + 512 + 768 + NN;  // pool..cnt contiguous

    int mmGrid = (NN + 127) / 128;   // 391
    int cGrid  = (NN + 63) / 64;     // 782
    int aGrid  = (NN + 3) / 4;       // 12500

    // ---- CSR build (once; reused by all 3 layers)
    k_prep<<<512, 256, 0, stream>>>((int*)pool, zeroN);
    k_hist<<<1024, 256, 0, stream>>>(dst, cnt);
    k_scanA<<<NB_SCAN, 256, 0, stream>>>(cnt, off, bsum);
    k_scanB<<<1, 256, 0, stream>>>(bsum, boff);
    k_scanC<<<NB_SCAN, 256, 0, stream>>>(cnt, off, boff, cur);
    k_scatter<<<1024, 256, 0, stream>>>(src, dst, cur, perm, srcs);

    for (int l = 0; l < 3; ++l) {
        const float* xc = (l == 0) ? x0 : xbuf;
        float* st = stats + l * 256;
        k_aggr<<<aGrid, 256, 0, stream>>>(xc, ea, leW + l * 1024, leb + l * 64,
                off, srcs, perm, eps, l, hbuf);
        k_mm64<0, 0><<<mmGrid, 128, 0, stream>>>(hbuf, W1 + l * 4096, b1 + l * 64,
                nullptr, nullptr, nullptr, hbuf, st);
        if (l < 2) {
            k_mm64<1, 0><<<mmGrid, 128, 0, stream>>>(hbuf, W2 + l * 4096, b2 + l * 64,
                    st, g1 + l * 64, bb1 + l * 64, hbuf, st + 128);
            k_bn<<<1024, 256, 0, stream>>>(hbuf, st + 128, og + l * 64, ob + l * 64, xbuf);
        } else {
            k_mm64<1, 1><<<mmGrid, 128, 0, stream>>>(hbuf, W2 + l * 4096, b2 + l * 64,
                    st, g1 + l * 64, bb1 + l * 64, xbuf, nullptr);
        }
    }
    k_pool<<<1024, 256, 0, stream>>>(xbuf, batch, pool);
    k_cmm<0><<<cGrid, 128, 0, stream>>>(xbuf, pool, batch, nullptr, nullptr, nullptr,
                                        cW1, cb1, h128, cstats);
    k_cmm<1><<<cGrid, 128, 0, stream>>>(h128, nullptr, nullptr, cstats, cg1, cbb1,
                                        cW2, cb2, h128, cstats + 256);
    k_out<<<1024, 256, 0, stream>>>(h128, cstats + 256, cg2, cbb2, cW3, cb3, outp);
}